// Round 8
// baseline (102.343 us; speedup 1.0000x reference)
//
#include <hip/hip_runtime.h>
#include <math.h>

// PhiCell hysteresis scan: s' = max(x-0.5, min(x+0.5, s)); output o_t = s_t.
// Associative scan over (lo,hi) clamp operators.
// R8: 2 kernels, NO LDS data staging. Evidence (R1==R3): coalescing is
// irrelevant here -- per-thread contiguous 8xfloat4 (128B wave stride) fully
// covers cache lines; kernels are BW-bound. Dropping the LDS transpose removes
// barriers + 2 LDS round-trips/elem from the critical path.

#define T_ELEMS 8388608
#define NEG_INF (-__builtin_inff())
#define POS_INF (__builtin_inff())

#define BLOCK   256
#define WAVES   4
#define F4T     8                         // float4 per thread (32 floats, contiguous)
#define EPB     (BLOCK * F4T * 4)         // 8192 floats per block
#define NBLK    (T_ELEMS / EPB)           // 1024
#define APT     (NBLK / BLOCK)            // 4 agg entries per thread in K2

struct Op { float lo, hi; };

// Apply operator a first, then b:  result(s) = b(a(s))
__device__ __forceinline__ Op combine(Op a, Op b) {
    Op r;
    r.lo = fmaxf(b.lo, fminf(b.hi, a.lo));
    r.hi = fminf(b.hi, a.hi);
    return r;
}
__device__ __forceinline__ float apply_op(Op o, float s) {
    return fmaxf(o.lo, fminf(o.hi, s));
}
__device__ __forceinline__ void fold_elem(Op& t, float e) {
    float elo = e - 0.5f, ehi = e + 0.5f;
    t.lo = fmaxf(elo, fminf(ehi, t.lo));
    t.hi = fminf(ehi, t.hi);
}
__device__ __forceinline__ void fold4(Op& t, float4 v) {
    fold_elem(t, v.x); fold_elem(t, v.y); fold_elem(t, v.z); fold_elem(t, v.w);
}

// Ordered wave-inclusive scan (lane order = time order).
__device__ __forceinline__ Op wave_incl_scan(Op t, int lane) {
#pragma unroll
    for (int off = 1; off < 64; off <<= 1) {
        float nlo = __shfl_up(t.lo, off);
        float nhi = __shfl_up(t.hi, off);
        if (lane >= off) {
            Op prev = { nlo, nhi };
            t = combine(prev, t);
        }
    }
    return t;
}
// Ordered wave reduction (result valid in lane 0).
__device__ __forceinline__ Op wave_reduce(Op t) {
#pragma unroll
    for (int off = 1; off < 64; off <<= 1) {
        Op nb;
        nb.lo = __shfl_down(t.lo, off);
        nb.hi = __shfl_down(t.hi, off);
        t = combine(t, nb);
    }
    return t;
}

// Load this thread's 32 time-contiguous floats (8 float4), scaled by wv.
__device__ __forceinline__ void load_thread(const float4* __restrict__ xg,
                                            size_t tbase, float wv, float4 v[F4T]) {
#pragma unroll
    for (int j = 0; j < F4T; ++j) {
        float4 t = xg[tbase + j];
        t.x *= wv; t.y *= wv; t.z *= wv; t.w *= wv;
        v[j] = t;
    }
}
// Fold 32 elements (time order) into one operator.
__device__ __forceinline__ Op fold_thread(const float4 v[F4T]) {
    Op t = { v[0].x - 0.5f, v[0].x + 0.5f };
    fold_elem(t, v[0].y); fold_elem(t, v[0].z); fold_elem(t, v[0].w);
#pragma unroll
    for (int k = 1; k < F4T; ++k) fold4(t, v[k]);
    return t;
}

// ---------------- K1: per-block aggregate operators ----------------
__global__ __launch_bounds__(BLOCK) void k1_agg(const float* __restrict__ x,
                                                const float* __restrict__ w,
                                                float2* __restrict__ agg) {
    __shared__ Op wt[WAVES];
    const int tid = threadIdx.x, lane = tid & 63, wid = tid >> 6;
    const float wv = w[0];
    const size_t tbase = ((size_t)blockIdx.x * BLOCK + tid) * F4T;
    const float4* xg = reinterpret_cast<const float4*>(x);

    float4 v[F4T];
    load_thread(xg, tbase, wv, v);
    Op t = wave_reduce(fold_thread(v));

    if (lane == 0) wt[wid] = t;
    __syncthreads();
    if (tid == 0) {
        Op bt = wt[0];
#pragma unroll
        for (int k = 1; k < WAVES; ++k) bt = combine(bt, wt[k]);
        agg[blockIdx.x] = make_float2(bt.lo, bt.hi);
    }
}

// ---------------- K2: per-block prefix fold + apply + store ----------------
__global__ __launch_bounds__(BLOCK) void k2_apply(const float* __restrict__ x,
                                                  const float* __restrict__ w,
                                                  const float* __restrict__ s0,
                                                  const float2* __restrict__ agg,
                                                  float* __restrict__ out) {
    __shared__ Op wtA[WAVES];              // per-wave inclusive totals (this block)
    __shared__ Op wtP[WAVES];              // prefix-fold partials
    const int tid = threadIdx.x, lane = tid & 63, wid = tid >> 6;
    const int b = blockIdx.x;
    const float wv = w[0];
    const size_t tbase = ((size_t)b * BLOCK + tid) * F4T;
    const float4* xg = reinterpret_cast<const float4*>(x);

    // issue tile loads first (independent), overlap with prefix fold
    float4 v[F4T];
    load_thread(xg, tbase, wv, v);

    // block-exclusive prefix E_b = ordered fold of agg[0..b-1]
    Op seg = { NEG_INF, POS_INF };
#pragma unroll
    for (int j = 0; j < APT; ++j) {
        int i = tid * APT + j;
        if (i < b) {
            float2 f = agg[i];
            Op o = { f.x, f.y };
            seg = combine(seg, o);
        }
    }
    seg = wave_reduce(seg);
    if (lane == 0) wtP[wid] = seg;

    // in-block scan
    Op t = fold_thread(v);
    Op incl = wave_incl_scan(t, lane);
    if (lane == 63) wtA[wid] = incl;
    __syncthreads();

    Op Eb = wtP[0];
#pragma unroll
    for (int k = 1; k < WAVES; ++k) Eb = combine(Eb, wtP[k]);

    Op wpre = { NEG_INF, POS_INF };
    for (int k = 0; k < wid; ++k) wpre = combine(wpre, wtA[k]);
    float elo = __shfl_up(incl.lo, 1);
    float ehi = __shfl_up(incl.hi, 1);
    Op excl;
    if (lane == 0) { excl.lo = NEG_INF; excl.hi = POS_INF; }
    else           { excl.lo = elo;     excl.hi = ehi;     }

    float s = apply_op(Eb, s0[0]);            // state entering this block
    s = apply_op(combine(wpre, excl), s);     // state entering this thread

    // apply 32 elems in registers; direct stores (same layout as loads)
    float4* og = reinterpret_cast<float4*>(out);
#pragma unroll
    for (int j = 0; j < F4T; ++j) {
        float4 e = v[j], o4;
        s = fmaxf(e.x - 0.5f, fminf(e.x + 0.5f, s)); o4.x = s;
        s = fmaxf(e.y - 0.5f, fminf(e.y + 0.5f, s)); o4.y = s;
        s = fmaxf(e.z - 0.5f, fminf(e.z + 0.5f, s)); o4.z = s;
        s = fmaxf(e.w - 0.5f, fminf(e.w + 0.5f, s)); o4.w = s;
        og[tbase + j] = o4;
    }

    if (b == NBLK - 1 && tid == BLOCK - 1)
        out[T_ELEMS] = s;                     // final state
}

extern "C" void kernel_launch(void* const* d_in, const int* in_sizes, int n_in,
                              void* d_out, int out_size, void* d_ws, size_t ws_size,
                              hipStream_t stream) {
    const float* x  = (const float*)d_in[0];   // (1, T) f32
    const float* w  = (const float*)d_in[1];   // (1, 1) f32
    const float* s0 = (const float*)d_in[2];   // (1, 1) f32
    float* out = (float*)d_out;                // [T outputs | final state]

    float2* agg = (float2*)d_ws;               // NBLK float2 (8 KB)

    k1_agg<<<NBLK, BLOCK, 0, stream>>>(x, w, agg);
    k2_apply<<<NBLK, BLOCK, 0, stream>>>(x, w, s0, agg, out);
}